// Round 3
// baseline (293.254 us; speedup 1.0000x reference)
//
#include <hip/hip_runtime.h>

// NeighbourCovariance: per vertex v, gather K=40 neighbors, weight features by
// exp(-10*distsq), compute per-feature weighted mean (C=3) and covariance (3x3).
// Output layout per vertex: [cov (F*9)] ++ [means (F*3)] = 384 floats.
//
// R3 structure: two-phase, float4-wide feature lanes.
//  Phase 1: block-cooperative. 32 vertices x K pairs; coalesced nidx/distsq,
//           one exp per pair, coord gather, stage (w,x,y,z)+feature offset in
//           LDS (row stride K+1 -> 8 vertices/wave hit distinct LDS banks).
//  Phase 2: lane = (vertex, 4-feature group). 8 lanes/vertex, each gathers a
//           float4 of the feature row (8x16B = one 128B coalesced row).
//           ~52 lane-ops of compute per gather -> latency amortized 4x vs R2.

constexpr int K = 40;
constexpr int KP = K + 1;   // padded LDS row stride (bank-conflict break)
constexpr int C = 3;
constexpr int F = 32;
constexpr float EPS = 1e-3f;
constexpr float DIST_SCALE = 10.0f;
constexpr int OUT_PER_V = F * C * C + F * C; // 384
constexpr int VPB = 32;                      // vertices per 256-thread block
constexpr int PAIRS = VPB * K;               // 1280

__global__ __launch_bounds__(256) void neighcov_kernel(
    const float* __restrict__ coords,    // V x 3
    const float* __restrict__ distsq,    // V x K
    const float* __restrict__ features,  // V x F
    const int*   __restrict__ nidx,      // V x K
    float* __restrict__ out,             // V x 384
    int V)
{
    __shared__ float4 s_wxyz[VPB * KP];  // (w, x, y, z) per (v,k)
    __shared__ int    s_joff[VPB * KP];  // j*F element offset into features

    const int tid   = threadIdx.x;
    const int vbase = blockIdx.x * VPB;
    const long long total_pairs = (long long)V * K;

    // ---- Phase 1: stage weights/coords, 1280 pairs, block-cooperative ----
    #pragma unroll
    for (int p = tid; p < PAIRS; p += 256) {
        const int vloc = p / K;          // const-div -> magic mul
        const int k    = p - vloc * K;
        const long long gp = (long long)(vbase + vloc) * K + k;
        int idx = -1;
        float d = 0.f;
        if (gp < total_pairs) {
            idx = nidx[gp];     // coalesced
            d   = distsq[gp];   // coalesced
        }
        const bool valid = (idx >= 0);
        const int j = valid ? idx : 0;
        const float w = valid ? __expf(-DIST_SCALE * d) : 0.f;
        const float x = coords[(size_t)j * 3 + 0];
        const float y = coords[(size_t)j * 3 + 1];
        const float z = coords[(size_t)j * 3 + 2];
        s_wxyz[vloc * KP + k] = make_float4(w, x, y, z);
        s_joff[vloc * KP + k] = j * F;
    }
    __syncthreads();

    // ---- Phase 2: lane = (vertex, feature-quad) ----
    const int g    = tid & 7;        // feature quad: features 4g..4g+3
    const int vloc = tid >> 3;       // 0..31
    const int v    = vbase + vloc;
    if (v >= V) return;

    const float4* wp = &s_wxyz[vloc * KP];
    const int*    jp = &s_joff[vloc * KP];

    float wsum[4] = {0.f, 0.f, 0.f, 0.f};
    float m0[4] = {0.f}, m1[4] = {0.f}, m2[4] = {0.f};
    float s00[4] = {0.f}, s01[4] = {0.f}, s02[4] = {0.f};
    float s11[4] = {0.f}, s12[4] = {0.f}, s22[4] = {0.f};

    #pragma unroll 4
    for (int k = 0; k < K; ++k) {
        const float4 q = wp[k];            // LDS: broadcast within vertex, padded across
        const int jo   = jp[k];
        const float4 ft = *(const float4*)(features + jo + 4 * g);  // 128B/row coalesced
        const float fv[4] = {ft.x, ft.y, ft.z, ft.w};
        const float x = q.y, y = q.z, z = q.w;
        #pragma unroll
        for (int i = 0; i < 4; ++i) {
            const float fw = fv[i] * q.x;  // w==0 encodes invalid neighbor
            const float fx = fw * x, fy = fw * y, fz = fw * z;
            wsum[i] += fw;
            m0[i] += fx;       m1[i] += fy;       m2[i] += fz;
            s00[i] += fx * x;  s01[i] += fx * y;  s02[i] += fx * z;
            s11[i] += fy * y;  s12[i] += fy * z;  s22[i] += fz * z;
        }
    }

    float* ov = out + (size_t)v * OUT_PER_V;
    #pragma unroll
    for (int i = 0; i < 4; ++i) {
        const float inv = 1.f / (wsum[i] + EPS);
        const float mu0 = m0[i] * inv, mu1 = m1[i] * inv, mu2 = m2[i] * inv;
        const float c00 = s00[i] * inv - mu0 * mu0;
        const float c01 = s01[i] * inv - mu0 * mu1;
        const float c02 = s02[i] * inv - mu0 * mu2;
        const float c11 = s11[i] * inv - mu1 * mu1;
        const float c12 = s12[i] * inv - mu1 * mu2;
        const float c22 = s22[i] * inv - mu2 * mu2;

        const int fglob = g * 4 + i;
        float* o = ov + fglob * 9;
        o[0] = c00; o[1] = c01; o[2] = c02;
        o[3] = c01; o[4] = c11; o[5] = c12;
        o[6] = c02; o[7] = c12; o[8] = c22;

        float* om = ov + F * 9 + fglob * 3;
        om[0] = mu0; om[1] = mu1; om[2] = mu2;
    }
}

extern "C" void kernel_launch(void* const* d_in, const int* in_sizes, int n_in,
                              void* d_out, int out_size, void* d_ws, size_t ws_size,
                              hipStream_t stream) {
    const float* coords   = (const float*)d_in[0];
    const float* distsq   = (const float*)d_in[1];
    const float* features = (const float*)d_in[2];
    const int*   nidx     = (const int*)d_in[3];
    float* out = (float*)d_out;

    const int V = in_sizes[0] / C;            // coordinates is V x 3
    const int blocks = (V + VPB - 1) / VPB;   // 32 vertices per 256-thread block

    neighcov_kernel<<<blocks, 256, 0, stream>>>(coords, distsq, features, nidx, out, V);
}

// Round 4
// 279.266 us; speedup vs baseline: 1.0501x; 1.0501x over previous
//
#include <hip/hip_runtime.h>
#include <hip/hip_fp16.h>

// NeighbourCovariance: per vertex v, gather K=40 neighbors, weight features by
// exp(-10*distsq), compute per-feature weighted mean (C=3) and covariance (3x3).
// Output layout per vertex: [cov (F*9)] ++ [means (F*3)] = 384 floats.
//
// R4 structure: three-phase, LDS-staged feature rows.
//  Phase 1:   320 (v,k) pairs: coalesced nidx/distsq, one exp per pair, coord
//             gather, stage (w,x,y,z) + feature row offset in LDS.
//  Phase 1.5: block-cooperative bulk gather of all 320 feature rows into LDS
//             as fp16 (features in [0,1) -> rel err ~5e-4, threshold 0.17).
//             10 INDEPENDENT float4 gathers per thread -> pure MLP, no
//             dependent load chain, latency-tolerant.
//  Phase 2:   lane = (vertex, feature). Inner loop reads ONLY LDS (feature
//             read = 16 banks x 2-way broadcast = conflict-free) + 14 VALU.
//             Zero vmcnt stalls in the hot loop.

constexpr int K = 40;
constexpr int C = 3;
constexpr int F = 32;
constexpr float EPS = 1e-3f;
constexpr float DIST_SCALE = 10.0f;
constexpr int OUT_PER_V = F * C * C + F * C; // 384
constexpr int VPB = 8;                        // vertices per 256-thread block
constexpr int ROWS = VPB * K;                 // 320 feature rows per block

__global__ __launch_bounds__(256) void neighcov_kernel(
    const float* __restrict__ coords,    // V x 3
    const float* __restrict__ distsq,    // V x K
    const float* __restrict__ features,  // V x F
    const int*   __restrict__ nidx,      // V x K
    float* __restrict__ out,             // V x 384
    int V)
{
    __shared__ float4 s_wxyz[ROWS];       // (w,x,y,z) per (v,k)          5120 B
    __shared__ int    s_joff[ROWS];       // j*F element offset           1280 B
    __shared__ __half s_feat[ROWS * F];   // fp16 feature rows           20480 B

    const int tid   = threadIdx.x;
    const int vbase = blockIdx.x * VPB;

    // ---- Phase 1: weights + coords + row offsets ----
    #pragma unroll
    for (int p = tid; p < ROWS; p += 256) {
        const int vloc = p / K;
        const int k    = p - vloc * K;
        const int vg   = vbase + vloc;
        int idx = -1;
        float d = 0.f;
        if (vg < V) {
            const size_t gp = (size_t)vg * K + k;
            idx = nidx[gp];     // coalesced
            d   = distsq[gp];   // coalesced
        }
        const bool valid = (idx >= 0);
        const int j = valid ? idx : 0;
        const float w = valid ? __expf(-DIST_SCALE * d) : 0.f;
        const float x = coords[(size_t)j * 3 + 0];
        const float y = coords[(size_t)j * 3 + 1];
        const float z = coords[(size_t)j * 3 + 2];
        s_wxyz[p] = make_float4(w, x, y, z);
        s_joff[p] = j * F;
    }
    __syncthreads();

    // ---- Phase 1.5: bulk-copy 320 feature rows -> LDS (fp16) ----
    // 2560 quad-tasks (row, 4-feature quad); 10 independent gathers/thread.
    #pragma unroll
    for (int q = tid; q < ROWS * 8; q += 256) {
        const int r    = q >> 3;
        const int quad = q & 7;
        const int jo   = s_joff[r];
        const float4 ft = *(const float4*)(features + jo + 4 * quad);
        union { __half2 h2[2]; uint2 u; } pk;
        pk.h2[0] = __floats2half2_rn(ft.x, ft.y);
        pk.h2[1] = __floats2half2_rn(ft.z, ft.w);
        *(uint2*)&s_feat[r * F + 4 * quad] = pk.u;  // 8B aligned LDS store
    }
    __syncthreads();

    // ---- Phase 2: lane = (vertex, feature); LDS-only inner loop ----
    const int f    = tid & (F - 1);
    const int vloc = tid >> 5;
    const int v    = vbase + vloc;
    if (v >= V) return;

    const float4* wp = &s_wxyz[vloc * K];
    const __half* fp = &s_feat[vloc * K * F + f];

    float wsum = 0.f;
    float m0 = 0.f, m1 = 0.f, m2 = 0.f;
    float s00 = 0.f, s01 = 0.f, s02 = 0.f, s11 = 0.f, s12 = 0.f, s22 = 0.f;

    #pragma unroll 8
    for (int k = 0; k < K; ++k) {
        const float4 q = wp[k];                      // broadcast (2 addrs/wave)
        const float feat = __half2float(fp[k * F]);  // 16 banks x 2-way: free
        const float fw = q.x * feat;                 // w==0 encodes invalid
        const float x = q.y, y = q.z, z = q.w;
        const float fx = fw * x, fy = fw * y, fz = fw * z;
        wsum += fw;
        m0 += fx;        m1 += fy;        m2 += fz;
        s00 += fx * x;   s01 += fx * y;   s02 += fx * z;
        s11 += fy * y;   s12 += fy * z;   s22 += fz * z;
    }

    const float inv = 1.f / (wsum + EPS);
    const float mu0 = m0 * inv, mu1 = m1 * inv, mu2 = m2 * inv;
    const float c00 = s00 * inv - mu0 * mu0;
    const float c01 = s01 * inv - mu0 * mu1;
    const float c02 = s02 * inv - mu0 * mu2;
    const float c11 = s11 * inv - mu1 * mu1;
    const float c12 = s12 * inv - mu1 * mu2;
    const float c22 = s22 * inv - mu2 * mu2;

    float* o = out + (size_t)v * OUT_PER_V + f * 9;
    o[0] = c00; o[1] = c01; o[2] = c02;
    o[3] = c01; o[4] = c11; o[5] = c12;
    o[6] = c02; o[7] = c12; o[8] = c22;

    float* om = out + (size_t)v * OUT_PER_V + F * 9 + f * 3;
    om[0] = mu0; om[1] = mu1; om[2] = mu2;
}

extern "C" void kernel_launch(void* const* d_in, const int* in_sizes, int n_in,
                              void* d_out, int out_size, void* d_ws, size_t ws_size,
                              hipStream_t stream) {
    const float* coords   = (const float*)d_in[0];
    const float* distsq   = (const float*)d_in[1];
    const float* features = (const float*)d_in[2];
    const int*   nidx     = (const int*)d_in[3];
    float* out = (float*)d_out;

    const int V = in_sizes[0] / C;            // coordinates is V x 3
    const int blocks = (V + VPB - 1) / VPB;   // 8 vertices per 256-thread block

    neighcov_kernel<<<blocks, 256, 0, stream>>>(coords, distsq, features, nidx, out, V);
}

// Round 5
// 258.588 us; speedup vs baseline: 1.1341x; 1.0800x over previous
//
#include <hip/hip_runtime.h>

// NeighbourCovariance: per vertex v, gather K=40 neighbors, weight features by
// exp(-10*distsq), compute per-feature weighted mean (C=3) and covariance (3x3).
// Output layout per vertex: [cov (F*9)] ++ [means (F*3)] = 384 floats.
//
// R5 structure: R2 two-phase + explicitly software-pipelined feature gathers.
//  Phase 1: 320 (v,k) pairs: coalesced nidx/distsq, ONE exp per pair, coord
//           gather, stage (w,x,y,z) + feature row offset in LDS (6.6 KB only).
//  Phase 2: lane = (vertex, feature). K processed in 5 blocks of 8 with a
//           register double-buffer: issue 8 INDEPENDENT feature gathers for
//           block b+1, then consume block b (8x13 FMA). This forces ~8
//           outstanding global loads per wave (R2's VGPR=36 proved the
//           compiler kept only ~1-2 in flight -> 50% vmcnt stalls).

constexpr int K = 40;
constexpr int C = 3;
constexpr int F = 32;
constexpr float EPS = 1e-3f;
constexpr float DIST_SCALE = 10.0f;
constexpr int OUT_PER_V = F * C * C + F * C; // 384
constexpr int VPB = 8;                        // vertices per 256-thread block
constexpr int PAIRS = VPB * K;                // 320
constexpr int KB = 8;                         // gather pipeline depth
constexpr int NBLK = K / KB;                  // 5

__global__ __launch_bounds__(256) void neighcov_kernel(
    const float* __restrict__ coords,    // V x 3
    const float* __restrict__ distsq,    // V x K
    const float* __restrict__ features,  // V x F
    const int*   __restrict__ nidx,      // V x K
    float* __restrict__ out,             // V x 384
    int V)
{
    __shared__ float4 s_wxyz[PAIRS];  // (w,x,y,z) per (v,k)   5120 B
    __shared__ int    s_joff[PAIRS];  // j*F element offset    1280 B

    const int tid   = threadIdx.x;
    const int vbase = blockIdx.x * VPB;

    // ---- Phase 1: weights + coords + row offsets ----
    #pragma unroll
    for (int p = tid; p < PAIRS; p += 256) {
        const int vloc = p / K;
        const int k    = p - vloc * K;
        const int vg   = vbase + vloc;
        int idx = -1;
        float d = 0.f;
        if (vg < V) {
            const size_t gp = (size_t)vg * K + k;
            idx = nidx[gp];     // coalesced
            d   = distsq[gp];   // coalesced
        }
        const bool valid = (idx >= 0);
        const int j = valid ? idx : 0;
        const float w = valid ? __expf(-DIST_SCALE * d) : 0.f;
        const float x = coords[(size_t)j * 3 + 0];
        const float y = coords[(size_t)j * 3 + 1];
        const float z = coords[(size_t)j * 3 + 2];
        s_wxyz[p] = make_float4(w, x, y, z);
        s_joff[p] = j * F;
    }
    __syncthreads();

    // ---- Phase 2: lane = (vertex, feature); pipelined gathers ----
    const int f    = tid & (F - 1);
    const int vloc = tid >> 5;
    const int v    = vbase + vloc;
    if (v >= V) return;

    const float4* wp = &s_wxyz[vloc * K];
    const int*    jp = &s_joff[vloc * K];  // 16B-aligned (K*4B = 160B stride)

    // All 40 row offsets up front as vector LDS reads -> addresses ready early.
    int joff[K];
    #pragma unroll
    for (int q = 0; q < K / 4; ++q)
        *(int4*)&joff[q * 4] = *(const int4*)&jp[q * 4];

    float wsum = 0.f;
    float m0 = 0.f, m1 = 0.f, m2 = 0.f;
    float s00 = 0.f, s01 = 0.f, s02 = 0.f, s11 = 0.f, s12 = 0.f, s22 = 0.f;

    float buf[2][KB];
    #pragma unroll
    for (int i = 0; i < KB; ++i)
        buf[0][i] = features[joff[i] + f];   // 8 independent gathers in flight

    #pragma unroll
    for (int kb = 0; kb < NBLK; ++kb) {
        const int cur = kb & 1, nxt = cur ^ 1;
        if (kb + 1 < NBLK) {
            #pragma unroll
            for (int i = 0; i < KB; ++i)     // issue next 8 before consuming
                buf[nxt][i] = features[joff[(kb + 1) * KB + i] + f];
        }
        #pragma unroll
        for (int i = 0; i < KB; ++i) {
            const float4 q = wp[kb * KB + i];   // broadcast LDS read
            const float fw = q.x * buf[cur][i]; // w==0 encodes invalid
            const float x = q.y, y = q.z, z = q.w;
            const float fx = fw * x, fy = fw * y, fz = fw * z;
            wsum += fw;
            m0 += fx;        m1 += fy;        m2 += fz;
            s00 += fx * x;   s01 += fx * y;   s02 += fx * z;
            s11 += fy * y;   s12 += fy * z;   s22 += fz * z;
        }
    }

    const float inv = 1.f / (wsum + EPS);
    const float mu0 = m0 * inv, mu1 = m1 * inv, mu2 = m2 * inv;
    const float c00 = s00 * inv - mu0 * mu0;
    const float c01 = s01 * inv - mu0 * mu1;
    const float c02 = s02 * inv - mu0 * mu2;
    const float c11 = s11 * inv - mu1 * mu1;
    const float c12 = s12 * inv - mu1 * mu2;
    const float c22 = s22 * inv - mu2 * mu2;

    float* o = out + (size_t)v * OUT_PER_V + f * 9;
    o[0] = c00; o[1] = c01; o[2] = c02;
    o[3] = c01; o[4] = c11; o[5] = c12;
    o[6] = c02; o[7] = c12; o[8] = c22;

    float* om = out + (size_t)v * OUT_PER_V + F * 9 + f * 3;
    om[0] = mu0; om[1] = mu1; om[2] = mu2;
}

extern "C" void kernel_launch(void* const* d_in, const int* in_sizes, int n_in,
                              void* d_out, int out_size, void* d_ws, size_t ws_size,
                              hipStream_t stream) {
    const float* coords   = (const float*)d_in[0];
    const float* distsq   = (const float*)d_in[1];
    const float* features = (const float*)d_in[2];
    const int*   nidx     = (const int*)d_in[3];
    float* out = (float*)d_out;

    const int V = in_sizes[0] / C;            // coordinates is V x 3
    const int blocks = (V + VPB - 1) / VPB;   // 8 vertices per 256-thread block

    neighcov_kernel<<<blocks, 256, 0, stream>>>(coords, distsq, features, nidx, out, V);
}